// Round 4
// baseline (591.974 us; speedup 1.0000x reference)
//
#include <hip/hip_runtime.h>

// VariableSelection (TFT-style) on gfx950. ALL I/O f32; bf16 MFMA internally.
// B=128 S=64 F=32 D=128 U=128 DS=128 DIN=262272, KMAIN=S*F*D=262144
// R4: k1 -> 512x512 dbuf, slab partials (no atomics) + k1r reduce; k0 coalesced.

typedef unsigned short u16;
typedef __attribute__((ext_vector_type(4))) u16 u16x4;
typedef __attribute__((ext_vector_type(8))) u16 u16x8;
typedef __attribute__((ext_vector_type(8))) __bf16 bf16x8;
typedef __attribute__((ext_vector_type(4))) float f32x4;

__device__ __forceinline__ u16 f2bf(float f) {
  unsigned int x = __float_as_uint(f);
  return (u16)((x + 0x7fffu + ((x >> 16) & 1u)) >> 16);  // RNE
}
__device__ __forceinline__ float eluf(float x) { return x > 0.f ? x : __expf(x) - 1.f; }
__device__ __forceinline__ float sigmoidf_(float x) { return 1.f / (1.f + __expf(-x)); }

#define MFMA_BF16(a, b, c) __builtin_amdgcn_mfma_f32_16x16x32_bf16((a), (b), (c), 0, 0, 0)

// ---------------------------------------------------------------------------
// K0: per-(f,mat) 128x128 transpose f32 -> bf16 [n][k]. 8x8 register micro-tile.
// grid 128 = f*4+mat, block 256 (16x16 micro-grid), fully coalesced loads.
// ---------------------------------------------------------------------------
__global__ __launch_bounds__(256) void k0_prep(
    const float* __restrict__ fWe, const float* __restrict__ fWl,
    const float* __restrict__ fWgl, const float* __restrict__ fWgs,
    u16* __restrict__ wT)
{
  const int b = blockIdx.x, f = b >> 2, mat = b & 3;
  const float* srcs[4] = {fWe, fWl, fWgl, fWgs};
  const float* src = srcs[mat] + (size_t)f * 16384;   // [k=128][n=128]
  u16* dst = wT + (size_t)b * 16384;                  // [n=128][k=128]
  const int ti = threadIdx.x >> 4, tj = threadIdx.x & 15;  // ti: k-block, tj: n-block
  float r[8][8];
#pragma unroll
  for (int j = 0; j < 8; ++j) {
    const float4 v0 = *(const float4*)(src + (size_t)(ti * 8 + j) * 128 + tj * 8);
    const float4 v1 = *(const float4*)(src + (size_t)(ti * 8 + j) * 128 + tj * 8 + 4);
    r[j][0] = v0.x; r[j][1] = v0.y; r[j][2] = v0.z; r[j][3] = v0.w;
    r[j][4] = v1.x; r[j][5] = v1.y; r[j][6] = v1.z; r[j][7] = v1.w;
  }
#pragma unroll
  for (int c = 0; c < 8; ++c) {
    u16x8 p;
#pragma unroll
    for (int j = 0; j < 8; ++j) p[j] = f2bf(r[j][c]);
    *(u16x8*)(dst + (size_t)(tj * 8 + c) * 128 + ti * 8) = p;
  }
}

// ---------------------------------------------------------------------------
// K1: split-K  he_pre = v[:, :262144] @ cWe,  res_pre = v @ cWp (fused A-share).
// grid nkb; block 512 (8 waves: waves 0-3 E, 4-7 P; wave = 32 rows).
// 32-k chunks, double-buffered LDS (60 KB -> 2 blocks/CU), reg prefetch.
// slabMode: write per-block partial slab (no atomics); else atomicAdd.
// ---------------------------------------------------------------------------
__global__ __launch_bounds__(512, 4) void k1_bigmm(
    const float* __restrict__ inp, const float* __restrict__ cWe,
    const float* __restrict__ cWp, float* __restrict__ part,
    float* __restrict__ heE, float* __restrict__ heP,
    int kiters, int slabMode)
{
  __shared__ __align__(16) u16 xA[2][128][40];   // v tile [m][k=32] bf16 (+pad)
  __shared__ __align__(16) u16 wE[2][128][40];   // cWe tile transposed [n][k=32]
  __shared__ __align__(16) u16 wP[2][128][40];   // cWp tile transposed [n][k=32]
  const int t = threadIdx.x;
  const int lane = t & 63, wv = t >> 6, quad = lane >> 4, l16 = lane & 15;
  const int mat = wv >> 2, mq = wv & 3;          // compute role
  const int arow = t >> 3, afo = t & 7;          // A staging: rows arow, arow+64
  const int wmi = t >> 8;                        // W staging: 0 -> E, 1 -> P
  const int tt = t & 255, km = tt >> 5, nb = tt & 31;  // 4k x 4n micro-tile
  const float* Wm = wmi ? cWp : cWe;

  f32x4 acc[2][8];
#pragma unroll
  for (int m = 0; m < 2; ++m)
#pragma unroll
    for (int n = 0; n < 8; ++n) { acc[m][n][0]=0.f; acc[m][n][1]=0.f; acc[m][n][2]=0.f; acc[m][n][3]=0.f; }

  const size_t kbase = (size_t)blockIdx.x * kiters * 32;

  float4 avr[2], wvr[4];
  auto load_regs = [&](int it) {
    const size_t kk = kbase + (size_t)it * 32;
    avr[0] = *(const float4*)(inp + (size_t)arow * 262144 + kk + afo * 4);
    avr[1] = *(const float4*)(inp + (size_t)(arow + 64) * 262144 + kk + afo * 4);
#pragma unroll
    for (int j = 0; j < 4; ++j)
      wvr[j] = *(const float4*)(Wm + (kk + (size_t)(km * 4 + j)) * 128 + nb * 4);
  };
  auto store_lds = [&](int buf) {
    u16x4 p0, p1;
    p0[0] = f2bf(avr[0].x); p0[1] = f2bf(avr[0].y); p0[2] = f2bf(avr[0].z); p0[3] = f2bf(avr[0].w);
    p1[0] = f2bf(avr[1].x); p1[1] = f2bf(avr[1].y); p1[2] = f2bf(avr[1].z); p1[3] = f2bf(avr[1].w);
    *(u16x4*)&xA[buf][arow][afo * 4] = p0;
    *(u16x4*)&xA[buf][arow + 64][afo * 4] = p1;
    u16 (*Wl)[40] = wmi ? wP[buf] : wE[buf];
#pragma unroll
    for (int c = 0; c < 4; ++c) {
      u16x4 q;
      q[0] = f2bf(((const float*)&wvr[0])[c]);
      q[1] = f2bf(((const float*)&wvr[1])[c]);
      q[2] = f2bf(((const float*)&wvr[2])[c]);
      q[3] = f2bf(((const float*)&wvr[3])[c]);
      *(u16x4*)&Wl[nb * 4 + c][km * 4] = q;
    }
  };

  load_regs(0);
  store_lds(0);
  for (int it = 0; it < kiters; ++it) {
    const int buf = it & 1;
    __syncthreads();                       // buf's stores visible to all
    if (it + 1 < kiters) load_regs(it + 1);
    u16 (*Wb)[40] = mat ? wP[buf] : wE[buf];
    const int ko = quad * 8;
    const bf16x8 a0 = *(const bf16x8*)&xA[buf][32 * mq + l16][ko];
    const bf16x8 a1 = *(const bf16x8*)&xA[buf][32 * mq + 16 + l16][ko];
#pragma unroll
    for (int nt = 0; nt < 8; ++nt) {
      const bf16x8 bfr = *(const bf16x8*)&Wb[nt * 16 + l16][ko];
      acc[0][nt] = MFMA_BF16(a0, bfr, acc[0][nt]);
      acc[1][nt] = MFMA_BF16(a1, bfr, acc[1][nt]);
    }
    if (it + 1 < kiters) store_lds(buf ^ 1);  // other buffer; vmcnt wait after MFMA
  }

  // C/D layout: col = lane&15, row = quad*4 + reg
  if (slabMode) {
    float* dst = part + (size_t)blockIdx.x * 32768 + (size_t)mat * 16384;
#pragma unroll
    for (int m = 0; m < 2; ++m)
#pragma unroll
      for (int nt = 0; nt < 8; ++nt)
#pragma unroll
        for (int r = 0; r < 4; ++r) {
          const int row = 32 * mq + m * 16 + quad * 4 + r;
          dst[row * 128 + nt * 16 + l16] = acc[m][nt][r];
        }
  } else {
    float* dst = mat ? heP : heE;
#pragma unroll
    for (int m = 0; m < 2; ++m)
#pragma unroll
      for (int nt = 0; nt < 8; ++nt)
#pragma unroll
        for (int r = 0; r < 4; ++r) {
          const int row = 32 * mq + m * 16 + quad * 4 + r;
          atomicAdd(&dst[row * 128 + nt * 16 + l16], acc[m][nt][r]);
        }
  }
}

// ---------------------------------------------------------------------------
// K1r: reduce nkb partial slabs -> he (32768 f32, [E|P]). 16-way k-split,
// float4 coalesced, atomic finish (contention 16, zeroed by host memset).
// grid 512 x 256.
// ---------------------------------------------------------------------------
__global__ __launch_bounds__(256) void k1_reduce(
    const float* __restrict__ part, float* __restrict__ he, int nkb)
{
  const int gid = blockIdx.x * 256 + threadIdx.x;   // [0, 131072)
  const int e4 = gid & 8191;                        // float4 element
  const int ks = gid >> 13;                         // [0, 16)
  const int slice = nkb >> 4;
  f32x4 s0 = {0.f,0.f,0.f,0.f}, s1 = {0.f,0.f,0.f,0.f};
  const float* p = part + (size_t)(ks * slice) * 32768 + (size_t)e4 * 4;
  for (int i = 0; i < slice; i += 2) {
    const f32x4 v0 = *(const f32x4*)(p + (size_t)i * 32768);
    const f32x4 v1 = *(const f32x4*)(p + (size_t)(i + 1) * 32768);
    s0 += v0; s1 += v1;
  }
  s0 += s1;
  float* o = he + e4 * 4;
  atomicAdd(&o[0], s0[0]); atomicAdd(&o[1], s0[1]);
  atomicAdd(&o[2], s0[2]); atomicAdd(&o[3], s0[3]);
}

// ---------------------------------------------------------------------------
// K1b: static tail + concat-GRN chain + LN + softmax -> w[B,F]
// grid 128 (block = batch row), block 512: u = t&127, dc = t>>7 splits d-loops 4x
// ---------------------------------------------------------------------------
__global__ __launch_bounds__(512) void k1b_small(
    const float* __restrict__ stat,
    const float* __restrict__ cWe, const float* __restrict__ cbe,
    const float* __restrict__ cWl, const float* __restrict__ cbl,
    const float* __restrict__ cWgl, const float* __restrict__ cbgl,
    const float* __restrict__ cWgs, const float* __restrict__ cbgs,
    const float* __restrict__ cgam, const float* __restrict__ cbet,
    const float* __restrict__ cWp, const float* __restrict__ cbp,
    const float* __restrict__ Ws, const float* __restrict__ bs,
    const float* __restrict__ preE, const float* __restrict__ preP,
    float* __restrict__ wout)
{
  const int b = blockIdx.x, t = threadIdx.x;
  const int u = t & 127, dc = t >> 7;
  __shared__ float shS[128], shA[128], shB[128], par[8][132], red[4];
  if (t < 128) shS[t] = stat[b * 128 + t];
  __syncthreads();

  const float* we = cWe + (size_t)262144 * 128;
  const float* wp = cWp + (size_t)262144 * 128;
  float hp = 0.f, rp = 0.f;
  for (int d = dc * 32; d < dc * 32 + 32; ++d) {
    const float sv = shS[d];
    hp += sv * we[d * 128 + u];
    rp += sv * wp[d * 128 + u];
  }
  par[dc][u] = hp; par[4 + dc][u] = rp;
  __syncthreads();

  float rs = 0.f;
  if (t < 128) {
    const float he = preE[b * 128 + t] + cbe[t] + par[0][t] + par[1][t] + par[2][t] + par[3][t];
    rs = preP[b * 128 + t] + cbp[t] + par[4][t] + par[5][t] + par[6][t] + par[7][t];
    shA[t] = eluf(he);
  }
  __syncthreads();

  float p = 0.f;
  for (int d = dc * 32; d < dc * 32 + 32; ++d) p += shA[d] * cWl[d * 128 + u];
  par[dc][u] = p;
  __syncthreads();
  if (t < 128) shB[t] = cbl[t] + par[0][t] + par[1][t] + par[2][t] + par[3][t];
  __syncthreads();

  float gp = 0.f, sp = 0.f;
  for (int d = dc * 32; d < dc * 32 + 32; ++d) {
    const float hv = shB[d];
    gp += hv * cWgl[d * 128 + u];
    sp += hv * cWgs[d * 128 + u];
  }
  par[dc][u] = gp; par[4 + dc][u] = sp;
  __syncthreads();

  float z = 0.f;
  if (t < 128) {
    const float gl = cbgl[t] + par[0][t] + par[1][t] + par[2][t] + par[3][t];
    const float gs = cbgs[t] + par[4][t] + par[5][t] + par[6][t] + par[7][t];
    z = rs + gl * sigmoidf_(gs);
  }
  float s = z, q = z * z;
#pragma unroll
  for (int off = 32; off >= 1; off >>= 1) { s += __shfl_xor(s, off); q += __shfl_xor(q, off); }
  if ((t & 63) == 0 && t < 128) { red[(t >> 6) * 2] = s; red[(t >> 6) * 2 + 1] = q; }
  __syncthreads();
  if (t < 128) {
    const float S = red[0] + red[2], Q = red[1] + red[3];
    const float mean = S * (1.f / 128.f);
    const float var = Q * (1.f / 128.f) - mean * mean;
    const float rstd = rsqrtf(var + 1e-3f);
    shA[t] = (z - mean) * rstd * cgam[t] + cbet[t];
  }
  __syncthreads();
  if (t < 32) {
    float sj = bs[t];
    for (int uu = 0; uu < 128; ++uu) sj += shA[uu] * Ws[uu * 32 + t];
    float m = sj;
#pragma unroll
    for (int off = 16; off >= 1; off >>= 1) m = fmaxf(m, __shfl_xor(m, off));
    const float e = __expf(sj - m);
    float se = e;
#pragma unroll
    for (int off = 16; off >= 1; off >>= 1) se += __shfl_xor(se, off);
    wout[b * 32 + t] = e / se;
  }
}

// ---------------------------------------------------------------------------
// K2 helpers
// ---------------------------------------------------------------------------
__device__ __forceinline__ void stage_wt(const u16* __restrict__ src, int kh,
                                         u16 WT[][72], int t)
{
  // src: pre-transposed bf16 [n=128][k=128]; copy k-half kh into WT[n][0..63]
#pragma unroll
  for (int i = 0; i < 4; ++i) {
    const int u = t + i * 256;
    const int n = u >> 3, k8 = u & 7;
    *(u16x8*)&WT[n][k8 * 8] = *(const u16x8*)(src + n * 128 + kh + k8 * 8);
  }
}

__device__ __forceinline__ void mm_half(const u16 A[][136], const u16 WT[][72],
                                        int wv, int quad, int l16, int kh, f32x4 acc[8])
{
#pragma unroll
  for (int ks = 0; ks < 2; ++ks) {
    const int kol = ks * 32 + quad * 8;
    const bf16x8 a = *(const bf16x8*)&A[16 * wv + l16][kh + kol];
#pragma unroll
    for (int nt = 0; nt < 8; ++nt) {
      const bf16x8 b = *(const bf16x8*)&WT[nt * 16 + l16][kol];
      acc[nt] = MFMA_BF16(a, b, acc[nt]);
    }
  }
}

// ---------------------------------------------------------------------------
// K2: per-feature GRN + LN + weighted combine over an 8-feature group held in
// registers; one atomicAdd per element per block (4 blocks/element total).
// grid 512 = fg(4, slow) x bb(128, fast); block 256 thr; M=64 rows, N=128.
// ---------------------------------------------------------------------------
__global__ __launch_bounds__(256) void k2_grn(
    const float* __restrict__ inp, const u16* __restrict__ wT,
    const float* __restrict__ fbe, const float* __restrict__ fbl,
    const float* __restrict__ fbgl, const float* __restrict__ fbgs,
    const float* __restrict__ fgam, const float* __restrict__ fbet,
    const float* __restrict__ wsel, float* __restrict__ out)
{
  __shared__ __align__(16) u16 xA[64][136];   // x tile bf16
  __shared__ __align__(16) u16 hA[64][136];   // h then h2
  __shared__ __align__(16) u16 WT[128][72];   // weight k-half, transposed [n][k]
  const int t = threadIdx.x;
  const int lane = t & 63, wv = t >> 6, quad = lane >> 4, l16 = lane & 15;
  const int bb = blockIdx.x & 127, fg = blockIdx.x >> 7;

  f32x4 acc[8], glr[8], racc[8];
#pragma unroll
  for (int n = 0; n < 8; ++n)
#pragma unroll
    for (int r = 0; r < 4; ++r) racc[n][r] = 0.f;

#define ZERO_ACC() do { _Pragma("unroll") \
  for (int n_ = 0; n_ < 8; ++n_) { acc[n_][0]=0.f; acc[n_][1]=0.f; acc[n_][2]=0.f; acc[n_][3]=0.f; } } while (0)

  for (int fi = 0; fi < 8; ++fi) {
    const int f = fg * 8 + fi;
    const float wb = wsel[bb * 32 + f];
    const u16* wf = wT + (size_t)f * 65536;   // 4 mats x [128][128]

    __syncthreads();  // previous iteration's xA/WT readers done
#pragma unroll
    for (int i = 0; i < 8; ++i) {
      const int u = t + i * 256;
      const int row = u >> 5, fo = u & 31;
      const float4 v = *(const float4*)(inp + (size_t)(bb * 64 + row) * 4096 + f * 128 + fo * 4);
      u16x4 p; p[0] = f2bf(v.x); p[1] = f2bf(v.y); p[2] = f2bf(v.z); p[3] = f2bf(v.w);
      *(u16x4*)&xA[row][fo * 4] = p;
    }

    // ---- stage 1: h = elu(x @ We + be) -> hA
    stage_wt(wf, 0, WT, t);
    __syncthreads();
    ZERO_ACC();
    mm_half(xA, WT, wv, quad, l16, 0, acc);
    __syncthreads();
    stage_wt(wf, 64, WT, t);
    __syncthreads();
    mm_half(xA, WT, wv, quad, l16, 64, acc);
#pragma unroll
    for (int nt = 0; nt < 8; ++nt) {
      const int col = nt * 16 + l16;
      const float bv = fbe[f * 128 + col];
#pragma unroll
      for (int r = 0; r < 4; ++r)
        hA[16 * wv + quad * 4 + r][col] = f2bf(eluf(acc[nt][r] + bv));
    }
    __syncthreads();

    // ---- stage 2: h2 = h @ Wl + bl -> hA
    stage_wt(wf + 16384, 0, WT, t);
    __syncthreads();
    ZERO_ACC();
    mm_half(hA, WT, wv, quad, l16, 0, acc);
    __syncthreads();
    stage_wt(wf + 16384, 64, WT, t);
    __syncthreads();
    mm_half(hA, WT, wv, quad, l16, 64, acc);
#pragma unroll
    for (int nt = 0; nt < 8; ++nt) {
      const int col = nt * 16 + l16;
      const float bv = fbl[f * 128 + col];
#pragma unroll
      for (int r = 0; r < 4; ++r)
        hA[16 * wv + quad * 4 + r][col] = f2bf(acc[nt][r] + bv);
    }
    __syncthreads();

    // ---- stage 3: gl = h2 @ Wgl + bgl (regs)
    stage_wt(wf + 2 * 16384, 0, WT, t);
    __syncthreads();
    ZERO_ACC();
    mm_half(hA, WT, wv, quad, l16, 0, acc);
    __syncthreads();
    stage_wt(wf + 2 * 16384, 64, WT, t);
    __syncthreads();
    mm_half(hA, WT, wv, quad, l16, 64, acc);
#pragma unroll
    for (int nt = 0; nt < 8; ++nt) {
      const int col = nt * 16 + l16;
      const float bv = fbgl[f * 128 + col];
#pragma unroll
      for (int r = 0; r < 4; ++r) glr[nt][r] = acc[nt][r] + bv;
    }
    __syncthreads();

    // ---- stage 4: gs = h2 @ Wgs + bgs
    stage_wt(wf + 3 * 16384, 0, WT, t);
    __syncthreads();
    ZERO_ACC();
    mm_half(hA, WT, wv, quad, l16, 0, acc);
    __syncthreads();
    stage_wt(wf + 3 * 16384, 64, WT, t);
    __syncthreads();
    mm_half(hA, WT, wv, quad, l16, 64, acc);

    // ---- epilogue: g = gl*sigmoid(gs); z = x + g; LN per row; racc += wb*xg
#pragma unroll
    for (int nt = 0; nt < 8; ++nt) {
      const int col = nt * 16 + l16;
      const float bv = fbgs[f * 128 + col];
#pragma unroll
      for (int r = 0; r < 4; ++r) {
        const float g = glr[nt][r] * sigmoidf_(acc[nt][r] + bv);
        const float x = __uint_as_float(((unsigned int)xA[16 * wv + quad * 4 + r][col]) << 16);
        acc[nt][r] = x + g;  // z
      }
    }
    float sm[4], sq[4];
#pragma unroll
    for (int r = 0; r < 4; ++r) {
      float s = 0.f, q = 0.f;
#pragma unroll
      for (int nt = 0; nt < 8; ++nt) { const float zz = acc[nt][r]; s += zz; q += zz * zz; }
      sm[r] = s; sq[r] = q;
    }
#pragma unroll
    for (int off = 1; off <= 8; off <<= 1)
#pragma unroll
      for (int r = 0; r < 4; ++r) { sm[r] += __shfl_xor(sm[r], off); sq[r] += __shfl_xor(sq[r], off); }
#pragma unroll
    for (int r = 0; r < 4; ++r) {
      const float mean = sm[r] * (1.f / 128.f);
      const float var = sq[r] * (1.f / 128.f) - mean * mean;
      const float rstd = rsqrtf(var + 1e-3f);
      sm[r] = mean; sq[r] = rstd;
    }
#pragma unroll
    for (int nt = 0; nt < 8; ++nt) {
      const int col = nt * 16 + l16;
      const float gam = fgam[f * 128 + col];
      const float bet = fbet[f * 128 + col];
#pragma unroll
      for (int r = 0; r < 4; ++r) {
        const float xg = (acc[nt][r] - sm[r]) * sq[r] * gam + bet;
        racc[nt][r] += wb * xg;
      }
    }
  }

#pragma unroll
  for (int nt = 0; nt < 8; ++nt) {
    const int col = nt * 16 + l16;
#pragma unroll
    for (int r = 0; r < 4; ++r) {
      const int grow = bb * 64 + 16 * wv + quad * 4 + r;
      atomicAdd(&out[(size_t)grow * 128 + col], racc[nt][r]);
    }
  }
#undef ZERO_ACC
}

extern "C" void kernel_launch(void* const* d_in, const int* in_sizes, int n_in,
                              void* d_out, int out_size, void* d_ws, size_t ws_size,
                              hipStream_t stream)
{
  const float* inp    = (const float*)d_in[0];
  const float* stat   = (const float*)d_in[1];
  const float* cWe    = (const float*)d_in[2];
  const float* cbe    = (const float*)d_in[3];
  const float* cWl    = (const float*)d_in[4];
  const float* cbl    = (const float*)d_in[5];
  const float* cWgl   = (const float*)d_in[6];
  const float* cbgl   = (const float*)d_in[7];
  const float* cWgs   = (const float*)d_in[8];
  const float* cbgs   = (const float*)d_in[9];
  const float* cgamma = (const float*)d_in[10];
  const float* cbeta  = (const float*)d_in[11];
  const float* cWp    = (const float*)d_in[12];
  const float* cbp    = (const float*)d_in[13];
  const float* Ws     = (const float*)d_in[14];
  const float* bs     = (const float*)d_in[15];
  const float* fbe    = (const float*)d_in[17];
  const float* fbl    = (const float*)d_in[19];
  const float* fbgl   = (const float*)d_in[21];
  const float* fbgs   = (const float*)d_in[23];
  const float* fgam   = (const float*)d_in[24];
  const float* fbet   = (const float*)d_in[25];
  const float* fWe    = (const float*)d_in[16];
  const float* fWl    = (const float*)d_in[18];
  const float* fWgl   = (const float*)d_in[20];
  const float* fWgs   = (const float*)d_in[22];

  // ws layout (f32 offsets):
  //   [0]       he/res accumulators  (32768: E 16384 | P 16384)
  //   [32768]   softmax weights w    (4096)
  //   [36864]   wT bf16 (2097152 u16 = 1048576 f32-equiv)
  //   [1085440] k1 partial slabs     (nkb * 32768)
  float* ws_he  = (float*)d_ws;
  float* ws_res = ws_he + 16384;
  float* ws_w   = ws_he + 32768;
  u16*   ws_wT  = (u16*)(ws_he + 36864);
  float* ws_sl  = ws_he + 1085440;

  // pick largest k-split whose slabs fit in ws
  int nkb = 0;
  const size_t base_bytes = (size_t)1085440 * 4;
  for (int cand = 512; cand >= 64; cand >>= 1) {
    if (ws_size >= base_bytes + (size_t)cand * 32768 * 4) { nkb = cand; break; }
  }

  hipMemsetAsync(d_out, 0, (size_t)out_size * sizeof(float), stream);  // k2 accumulator
  hipMemsetAsync(ws_he, 0, 32768 * sizeof(float), stream);             // he/res (k1r or atomic)
  k0_prep<<<128, 256, 0, stream>>>(fWe, fWl, fWgl, fWgs, ws_wT);

  if (nkb > 0) {
    const int kiters = 8192 / nkb;
    k1_bigmm<<<nkb, 512, 0, stream>>>(inp, cWe, cWp, ws_sl, ws_he, ws_res, kiters, 1);
    k1_reduce<<<512, 256, 0, stream>>>(ws_sl, ws_he, nkb);
  } else {
    k1_bigmm<<<256, 512, 0, stream>>>(inp, cWe, cWp, ws_sl, ws_he, ws_res, 32, 0);
  }
  k1b_small<<<128, 512, 0, stream>>>(stat, cWe, cbe, cWl, cbl, cWgl, cbgl, cWgs, cbgs,
                                     cgamma, cbeta, cWp, cbp, Ws, bs, ws_he, ws_res, ws_w);
  k2_grn<<<512, 256, 0, stream>>>(inp, ws_wT, fbe, fbl, fbgl, fbgs,
                                  fgam, fbet, ws_w, (float*)d_out);
}